// Round 1
// baseline (536.555 us; speedup 1.0000x reference)
//
#include <hip/hip_runtime.h>
#include <hip/hip_bf16.h>
#include <math.h>

// LGCN layer, restructured:
//   agg = segsum(atten * (src@W_rel)) == segsum(atten*src) @ W_rel   (linearity)
//   att_logit = s1[src] + s2[dst],  s1 = feat@lin_w[:64]+b, s2 = feat@lin_w[64:]
// Pipeline: memset ws -> precompute s1/s2 -> edge scatter (atomic) -> node finalize.

#define D 64

// ---------------- kernel 1: per-node attention scalars ----------------
__global__ __launch_bounds__(256) void precompute_att(
    const float* __restrict__ feat, const float* __restrict__ lin_w,
    const float* __restrict__ lin_b, float* __restrict__ s1,
    float* __restrict__ s2, int N) {
  const int lane = threadIdx.x & 63;
  const int wid  = (blockIdx.x * blockDim.x + threadIdx.x) >> 6;
  const int nw   = (gridDim.x * blockDim.x) >> 6;
  const float w1 = lin_w[lane];
  const float w2 = lin_w[64 + lane];
  const float b  = lin_b[0];
  for (int i = wid; i < N; i += nw) {
    const float f = feat[(size_t)i * D + lane];
    float v1 = f * w1;
    float v2 = f * w2;
    #pragma unroll
    for (int off = 32; off > 0; off >>= 1) {
      v1 += __shfl_down(v1, off, 64);
      v2 += __shfl_down(v2, off, 64);
    }
    if (lane == 0) {
      s1[i] = v1 + b;   // fold bias into s1
      s2[i] = v2;
    }
  }
}

// ---------------- kernel 2: edge scatter (the hot one) ----------------
__global__ __launch_bounds__(256) void edge_scatter(
    const int* __restrict__ esrc, const int* __restrict__ edst,
    const float* __restrict__ feat, const float* __restrict__ s1,
    const float* __restrict__ s2, float* __restrict__ acc,
    int* __restrict__ hasmsg, int E) {
  const int lane = threadIdx.x & 63;
  // make the wave slot provably uniform so edge-id / s1 / s2 loads go scalar
  const int wslot = __builtin_amdgcn_readfirstlane(threadIdx.x >> 6);
  const int wid   = blockIdx.x * (blockDim.x >> 6) + wslot;
  const int nw    = gridDim.x * (blockDim.x >> 6);
  for (int e = wid; e < E; e += nw) {
    const int src = esrc[e];
    const int dst = edst[e];
    const float logit = s1[src] + s2[dst];
    // sigmoid(relu(x)); always >= 0.5, never skippable
    const float a = 1.0f / (1.0f + __expf(-fmaxf(logit, 0.0f)));
    const float f = feat[(size_t)src * D + lane];
    unsafeAtomicAdd(&acc[(size_t)dst * D + lane], a * f);  // hw global_atomic_add_f32
    if (lane == 0) hasmsg[dst] = 1;  // racy but all writers store 1
  }
}

// ---------------- kernel 3: node finalize (matvecs + epilogue) ----------------
__global__ __launch_bounds__(256) void node_finalize(
    const float* __restrict__ feat, const float* __restrict__ norm,
    const float* __restrict__ acc, const int* __restrict__ hasmsg,
    const float* __restrict__ W_rel, const float* __restrict__ loop_w,
    const float* __restrict__ evolve_w, float* __restrict__ out, int N) {
  __shared__ float sWrel[D * D];   // 16 KB
  __shared__ float sWl[D * D];     // 16 KB
  __shared__ float sWe[D * D];     // 16 KB
  for (int i = threadIdx.x; i < D * D; i += 256) {
    sWrel[i] = W_rel[i];
    sWl[i]   = loop_w[i];
    sWe[i]   = evolve_w[i];
  }
  __syncthreads();

  const int lane = threadIdx.x & 63;
  const int wid  = blockIdx.x * 4 + (threadIdx.x >> 6);
  const int nw   = gridDim.x * 4;
  for (int i = wid; i < N; i += nw) {
    const float f  = feat[(size_t)i * D + lane];
    const float n  = norm[i];
    const int   hm = hasmsg[i];
    float nf, lm = 0.0f;
    if (hm) {
      const float p = acc[(size_t)i * D + lane];
      float a1 = 0.0f;
      #pragma unroll 8
      for (int k = 0; k < D; ++k) {
        const float fb = __shfl(f, k, 64);
        const float pb = __shfl(p, k, 64);
        a1 += pb * sWrel[k * D + lane];
        lm += fb * sWl[k * D + lane];
      }
      nf = a1 * n;
    } else {
      #pragma unroll 8
      for (int k = 0; k < D; ++k) {
        const float fb = __shfl(f, k, 64);
        lm += fb * sWe[k * D + lane];
      }
      nf = f * n;  // zero in-degree keeps old feat
    }
    out[(size_t)i * D + lane] = tanhf(nf + lm);
  }
}

extern "C" void kernel_launch(void* const* d_in, const int* in_sizes, int n_in,
                              void* d_out, int out_size, void* d_ws, size_t ws_size,
                              hipStream_t stream) {
  const float* feat     = (const float*)d_in[0];
  const float* norm     = (const float*)d_in[1];
  const int*   esrc     = (const int*)d_in[2];
  const int*   edst     = (const int*)d_in[3];
  // d_in[4] = etype: provably a no-op permutation in the reference
  const float* W_rel    = (const float*)d_in[5];
  const float* lin_w    = (const float*)d_in[6];
  const float* lin_b    = (const float*)d_in[7];
  const float* loop_w   = (const float*)d_in[8];
  const float* evolve_w = (const float*)d_in[9];
  float* out = (float*)d_out;

  const int N = in_sizes[1];   // norm is [N]
  const int E = in_sizes[2];   // edge_src is [E]

  // workspace layout: acc[N*D] f32 | hasmsg[N] i32 | s1[N] f32 | s2[N] f32
  float* acc    = (float*)d_ws;
  int*   hasmsg = (int*)(acc + (size_t)N * D);
  float* s1     = (float*)(hasmsg + N);
  float* s2     = s1 + N;

  // zero acc + hasmsg (ws is poisoned 0xAA before every timed launch)
  hipMemsetAsync(d_ws, 0, ((size_t)N * D + N) * sizeof(float), stream);

  precompute_att<<<512, 256, 0, stream>>>(feat, lin_w, lin_b, s1, s2, N);
  edge_scatter<<<8192, 256, 0, stream>>>(esrc, edst, feat, s1, s2, acc, hasmsg, E);
  node_finalize<<<1024, 256, 0, stream>>>(feat, norm, acc, hasmsg, W_rel, loop_w,
                                          evolve_w, out, N);
}